// Round 1
// baseline (165.090 us; speedup 1.0000x reference)
//
#include <hip/hip_runtime.h>
#include <math.h>

#define NOBS 7
#define TWO_PI_F 6.283185307179586f

// ---------------- gate helpers (state: sre/smm[1024] in LDS) ----------------

// general 1-qubit complex gate on bit p (512 pairs, 2 per thread)
__device__ __forceinline__ void gate1q_generic(
    float* re, float* im, int tid, int p,
    float u00r, float u00i, float u01r, float u01i,
    float u10r, float u10i, float u11r, float u11i)
{
#pragma unroll
  for (int r = 0; r < 2; ++r) {
    int k = tid + r * 256;
    int i0 = ((k >> p) << (p + 1)) | (k & ((1 << p) - 1));
    int i1 = i0 | (1 << p);
    float ar = re[i0], ai = im[i0], br = re[i1], bi = im[i1];
    re[i0] = u00r * ar - u00i * ai + u01r * br - u01i * bi;
    im[i0] = u00r * ai + u00i * ar + u01r * bi + u01i * br;
    re[i1] = u10r * ar - u10i * ai + u11r * br - u11i * bi;
    im[i1] = u10r * ai + u10i * ar + u11r * bi + u11i * br;
  }
}

// RY on bit p; angle table indexed by (ancilla<<6-ish): ai = (i0&3)*selmul + idx
__device__ __forceinline__ void ry_step(
    float* re, float* im, int tid, int p,
    const float* ct, const float* st, int idx, int selmul, float sgn)
{
#pragma unroll
  for (int r = 0; r < 2; ++r) {
    int k = tid + r * 256;
    int i0 = ((k >> p) << (p + 1)) | (k & ((1 << p) - 1));
    int i1 = i0 | (1 << p);
    int ai_ = (i0 & 3) * selmul + idx;
    float c = ct[ai_], s = sgn * st[ai_];
    float a0r = re[i0], a0i = im[i0], a1r = re[i1], a1i = im[i1];
    re[i0] = c * a0r - s * a1r; im[i0] = c * a0i - s * a1i;
    re[i1] = s * a0r + c * a1r; im[i1] = s * a0i + c * a1i;
  }
}

// CRX: control bit pc (==1), target bit pt. 256 pairs, 1 per thread.
// new_a = c*a - i*s*b ; new_b = -i*s*a + c*b
__device__ __forceinline__ void crx_step(
    float* re, float* im, int tid, int pc, int pt,
    const float* ct, const float* st, int idx, int selmul, float sgn)
{
  int lo = pc < pt ? pc : pt;
  int hi = pc < pt ? pt : pc;
  int t1 = ((tid >> lo) << (lo + 1)) | (tid & ((1 << lo) - 1));
  int t2 = ((t1 >> hi) << (hi + 1)) | (t1 & ((1 << hi) - 1));
  int i0 = t2 | (1 << pc);
  int i1 = i0 | (1 << pt);
  int ai_ = (i0 & 3) * selmul + idx;
  float c = ct[ai_], s = sgn * st[ai_];
  float ar = re[i0], ai = im[i0], br = re[i1], bi = im[i1];
  re[i0] = c * ar + s * bi;  im[i0] = c * ai - s * br;
  re[i1] = c * br + s * ai;  im[i1] = c * bi - s * ar;
}

// CNOT control bit1, target bit0 (ancilla wires 8->bit1, 9->bit0)
__device__ __forceinline__ void cnot_anc(float* re, float* im, int tid)
{
  int i0 = (tid << 2) | 2, i1 = i0 | 1;
  float tr = re[i0], ti = im[i0];
  re[i0] = re[i1]; im[i0] = im[i1];
  re[i1] = tr;     im[i1] = ti;
}

// pcphase: multiply by e^{+i phi} if (idx&3)==0 else e^{-i phi}
__device__ __forceinline__ void pcphase_step(float* re, float* im, int tid,
                                             float cph, float sph)
{
#pragma unroll
  for (int r = 0; r < 4; ++r) {
    int i = tid + r * 256;
    float sp = ((i & 3) == 0) ? sph : -sph;
    float ar = re[i], ai = im[i];
    re[i] = cph * ar - sp * ai;
    im[i] = sp * ar + cph * ai;
  }
}

// ---------------- sim14 ansatz layers (NQ=8, wire w -> bit 9-w) ----------------

__device__ void sim14_layer_fwd(float* re, float* im, int tid,
                                const float* ct, const float* st, int off, int selmul)
{
  for (int i = 0; i < 8; ++i) { ry_step(re, im, tid, 9 - i, ct, st, off + i, selmul, 1.f); __syncthreads(); }
  for (int j = 0; j < 8; ++j) { int i = 7 - j;
    crx_step(re, im, tid, 9 - i, 9 - ((i + 1) & 7), ct, st, off + 8 + j, selmul, 1.f); __syncthreads(); }
  for (int i = 0; i < 8; ++i) { ry_step(re, im, tid, 9 - i, ct, st, off + 16 + i, selmul, 1.f); __syncthreads(); }
  for (int j = 0; j < 8; ++j) { int i = (j == 0) ? 7 : (j - 1);
    crx_step(re, im, tid, 9 - i, 9 - ((i + 7) & 7), ct, st, off + 24 + j, selmul, 1.f); __syncthreads(); }
}

__device__ void sim14_layer_adj(float* re, float* im, int tid,
                                const float* ct, const float* st, int off, int selmul)
{
  for (int j = 7; j >= 0; --j) { int i = (j == 0) ? 7 : (j - 1);
    crx_step(re, im, tid, 9 - i, 9 - ((i + 7) & 7), ct, st, off + 24 + j, selmul, -1.f); __syncthreads(); }
  for (int i = 7; i >= 0; --i) { ry_step(re, im, tid, 9 - i, ct, st, off + 16 + i, selmul, -1.f); __syncthreads(); }
  for (int j = 7; j >= 0; --j) { int i = 7 - j;
    crx_step(re, im, tid, 9 - i, 9 - ((i + 1) & 7), ct, st, off + 8 + j, selmul, -1.f); __syncthreads(); }
  for (int i = 7; i >= 0; --i) { ry_step(re, im, tid, 9 - i, ct, st, off + i, selmul, -1.f); __syncthreads(); }
}

// ---------------- prepare (ancilla wires; fused RY*RZ per qubit) ----------------

__device__ void prepare_fwd(float* re, float* im, int tid,
                            const float* cpr, const float* spr)
{
  for (int ly = 0; ly < 2; ++ly) {
    for (int qi = 0; qi < 2; ++qi) {
      int b4 = ly * 4 + qi * 2;
      float cy = cpr[b4], sy = spr[b4], cz = cpr[b4 + 1], sz = spr[b4 + 1];
      // U = Rz(z) * Ry(y)
      gate1q_generic(re, im, tid, 1 - qi,
                     cy * cz, -cy * sz,  -sy * cz,  sy * sz,
                     sy * cz,  sy * sz,   cy * cz,  cy * sz);
      __syncthreads();
    }
    cnot_anc(re, im, tid);
    __syncthreads();
  }
}

__device__ void prepare_adj(float* re, float* im, int tid,
                            const float* cpr, const float* spr)
{
  for (int ly = 1; ly >= 0; --ly) {
    cnot_anc(re, im, tid);
    __syncthreads();
    for (int qi = 1; qi >= 0; --qi) {
      int b4 = ly * 4 + qi * 2;
      float cy = cpr[b4], sy = spr[b4], cz = cpr[b4 + 1], sz = spr[b4 + 1];
      // U^dagger of the forward fused gate
      gate1q_generic(re, im, tid, 1 - qi,
                     cy * cz,  cy * sz,   sy * cz, -sy * sz,
                    -sy * cz, -sy * sz,   cy * cz, -cy * sz);
      __syncthreads();
    }
  }
}

// ---------------- main kernel: one block per batch element ----------------

__global__ __launch_bounds__(256) void qsvt_kernel(
    const float* __restrict__ z_t, const float* __restrict__ t,
    const float* __restrict__ te_w1, const float* __restrict__ te_b1,
    const float* __restrict__ te_w2, const float* __restrict__ te_b2,
    const float* __restrict__ ip_w1, const float* __restrict__ ip_b1,
    const float* __restrict__ ip_w2, const float* __restrict__ ip_b2,
    const float* __restrict__ prep_p, const float* __restrict__ sig,
    const float* __restrict__ qff, const float* __restrict__ A_obs,
    const float* __restrict__ B_obs, const float* __restrict__ D_obs,
    const float* __restrict__ head_w, const float* __restrict__ head_b,
    float* __restrict__ out)
{
  __shared__ float sre[1024];
  __shared__ float smm[1024];
  __shared__ float csel[256], ssel[256];   // cos/sin of ts/2, laid out [s*64+idx]
  __shared__ float cpr[8], spr[8];         // prep_params half-angle trig
  __shared__ float csg[4], ssg[4];         // signal angles (full angle)
  __shared__ float cqf[32], sqf[32];       // qff half-angle trig
  __shared__ float hd[NOBS][4], hx[NOBS][6], hy[NOBS][6];
  __shared__ float ev[NOBS];
  __shared__ float red[NOBS][4];

  const int tid = threadIdx.x;
  const int b = blockIdx.x;

  // ===== Phase A: MLP (temb->csel[0:128], y1->ssel[0:128], hin->sre[0:256], h1->smm[0:256]) =====
  if (tid < 64) {
    float fr = expf(-logf(10000.f) * (float)tid / 64.f);
    float arg = t[b] * fr;
    csel[tid]      = cosf(arg);
    csel[64 + tid] = sinf(arg);
  }
  __syncthreads();
  if (tid < 128) {
    const float* wrow = te_w1 + tid * 128;
    float acc = te_b1[tid];
    for (int j = 0; j < 128; ++j) acc += wrow[j] * csel[j];
    ssel[tid] = acc / (1.f + expf(-acc));  // silu
  }
  __syncthreads();
  if (tid < 128) {
    const float* wrow = te_w2 + tid * 128;
    float acc = te_b2[tid];
    for (int j = 0; j < 128; ++j) acc += wrow[j] * ssel[j];
    sre[128 + tid] = acc;              // t_emb part of hin
    sre[tid] = z_t[b * 128 + tid];     // z_t part of hin
  }
  __syncthreads();
  {
    const float* wrow = ip_w1 + tid * 256;
    float acc = ip_b1[tid];
    for (int j = 0; j < 256; ++j) acc += wrow[j] * sre[j];
    smm[tid] = acc / (1.f + expf(-acc));  // silu
  }
  __syncthreads();
  float theta;
  {
    const float* wrow = ip_w2 + tid * 256;
    float acc = ip_b2[tid];
    for (int j = 0; j < 256; ++j) acc += wrow[j] * smm[j];
    float sg = 1.f / (1.f + expf(-acc));
    theta = sg * TWO_PI_F;               // ts[b][tid/64][tid%64]
  }
  __syncthreads();

  // ===== Phase B: constants + state init =====
  csel[tid] = cosf(0.5f * theta);
  ssel[tid] = sinf(0.5f * theta);
  if (tid < 8)                    { float a = prep_p[tid]; cpr[tid] = cosf(0.5f * a); spr[tid] = sinf(0.5f * a); }
  else if (tid >= 32 && tid < 36) { float a = sig[tid - 32]; csg[tid - 32] = cosf(a); ssg[tid - 32] = sinf(a); }
  else if (tid >= 64 && tid < 96) { float a = qff[tid - 64]; cqf[tid - 64] = cosf(0.5f * a); sqf[tid - 64] = sinf(0.5f * a); }
  else if (tid >= 128 && tid < 128 + NOBS) {
    int w = tid - 128;
    hd[w][0] = 2.f * D_obs[w * 4 + 1];
    hd[w][1] = 2.f * D_obs[w * 4 + 2];
    hd[w][2] = 2.f * D_obs[w * 4 + 3];
    hd[w][3] = 0.f;
    for (int k = 0; k < 6; ++k) { hx[w][k] = A_obs[w * 6 + k]; hy[w][k] = B_obs[w * 6 + k]; }
  }
#pragma unroll
  for (int r = 0; r < 4; ++r) { int i = tid + r * 256; sre[i] = (i == 0) ? 1.f : 0.f; smm[i] = 0.f; }
  __syncthreads();

  // ===== Phase C: QSVT circuit =====
  pcphase_step(sre, smm, tid, csg[0], ssg[0]);
  __syncthreads();

  for (int k = 0; k < 3; ++k) {
    prepare_fwd(sre, smm, tid, cpr, spr);
    if (k & 1) {  // adjoint select: reverse layer order, reversed ops, negated angles
      sim14_layer_adj(sre, smm, tid, csel, ssel, 32, 64);
      sim14_layer_adj(sre, smm, tid, csel, ssel, 0, 64);
    } else {
      sim14_layer_fwd(sre, smm, tid, csel, ssel, 0, 64);
      sim14_layer_fwd(sre, smm, tid, csel, ssel, 32, 64);
    }
    prepare_adj(sre, smm, tid, cpr, spr);
    pcphase_step(sre, smm, tid, csg[k + 1], ssg[k + 1]);
    __syncthreads();
  }

  // final sim14, 1 layer, global qff angles
  sim14_layer_fwd(sre, smm, tid, cqf, sqf, 0, 0);

  // ===== Phase D: observables  e_w = sum_groups v^H H_w v =====
  float accw[NOBS];
#pragma unroll
  for (int w = 0; w < NOBS; ++w) {
    int pb = 8 - w;  // wires (w, w+1) -> bits (9-w, 8-w); pa = pb+1
    int ib = ((tid >> pb) << (pb + 2)) | (tid & ((1 << pb) - 1));
    float vr[4], vi[4];
#pragma unroll
    for (int i = 0; i < 4; ++i) { vr[i] = sre[ib + (i << pb)]; vi[i] = smm[ib + (i << pb)]; }
    float a = hd[w][0] * (vr[0] * vr[0] + vi[0] * vi[0])
            + hd[w][1] * (vr[1] * vr[1] + vi[1] * vi[1])
            + hd[w][2] * (vr[2] * vr[2] + vi[2] * vi[2]);
    const int oi[6] = {1, 2, 2, 3, 3, 3};
    const int oj[6] = {0, 0, 1, 0, 1, 2};
#pragma unroll
    for (int k2 = 0; k2 < 6; ++k2) {
      int i = oi[k2], j = oj[k2];
      float rr = vr[i] * vr[j] + vi[i] * vi[j];   // Re(conj(v_i) v_j)
      float ii = vr[i] * vi[j] - vi[i] * vr[j];   // Im(conj(v_i) v_j)
      a += 2.f * (hx[w][k2] * rr - hy[w][k2] * ii);
    }
    accw[w] = a;
  }
  int lane = tid & 63, wv = tid >> 6;
#pragma unroll
  for (int w = 0; w < NOBS; ++w) {
    float v = accw[w];
    for (int o = 32; o > 0; o >>= 1) v += __shfl_down(v, o, 64);
    if (lane == 0) red[w][wv] = v;
  }
  __syncthreads();
  if (tid < NOBS) ev[tid] = red[tid][0] + red[tid][1] + red[tid][2] + red[tid][3];
  __syncthreads();

  // ===== Phase E: head =====
  if (tid < 128) {
    float o = head_b[tid];
#pragma unroll
    for (int w = 0; w < NOBS; ++w) o += ev[w] * head_w[tid * NOBS + w];
    out[b * 128 + tid] = o;
  }
}

extern "C" void kernel_launch(void* const* d_in, const int* in_sizes, int n_in,
                              void* d_out, int out_size, void* d_ws, size_t ws_size,
                              hipStream_t stream) {
  (void)n_in; (void)out_size; (void)d_ws; (void)ws_size;
  const float* z_t    = (const float*)d_in[0];
  const float* t      = (const float*)d_in[1];
  const float* te_w1  = (const float*)d_in[2];
  const float* te_b1  = (const float*)d_in[3];
  const float* te_w2  = (const float*)d_in[4];
  const float* te_b2  = (const float*)d_in[5];
  const float* ip_w1  = (const float*)d_in[6];
  const float* ip_b1  = (const float*)d_in[7];
  const float* ip_w2  = (const float*)d_in[8];
  const float* ip_b2  = (const float*)d_in[9];
  const float* prep_p = (const float*)d_in[10];
  const float* sig    = (const float*)d_in[11];
  const float* qff    = (const float*)d_in[12];
  const float* A_obs  = (const float*)d_in[13];
  const float* B_obs  = (const float*)d_in[14];
  const float* D_obs  = (const float*)d_in[15];
  const float* head_w = (const float*)d_in[16];
  const float* head_b = (const float*)d_in[17];
  float* out = (float*)d_out;

  int B = in_sizes[1];  // t is (B,)
  qsvt_kernel<<<B, 256, 0, stream>>>(
      z_t, t, te_w1, te_b1, te_w2, te_b2, ip_w1, ip_b1, ip_w2, ip_b2,
      prep_p, sig, qff, A_obs, B_obs, D_obs, head_w, head_b, out);
}